// Round 1
// baseline (62.458 us; speedup 1.0000x reference)
//
#include <hip/hip_runtime.h>

// Chamfer loss: pred (8,4096,3) f32, target (8,4096,3) f32 -> scalar f32.
// dist(q,t) = ||q||^2 + ||t||^2 - 2 q.t  (same formula as reference)
// out = mean_n min_m dist + mean_m min_n dist

#define BATCH 8
#define NPTS  4096
#define TPB   256
#define Q     8                   // queries per thread
#define CHUNK 512                 // target points staged in LDS per block
#define QTILE (TPB * Q)           // 2048 queries per block
#define NQT   (NPTS / QTILE)      // 2
#define NCH   (NPTS / CHUNK)      // 8

// Partial-min kernel: each block = (dir, batch, query-tile, target-chunk).
// Stages CHUNK targets as float4(x,y,z,|t|^2) in LDS; each thread owns Q
// queries; per target j: 1 add + 3 fma + 1 min per query (5 VALU/pair).
// Result merged cross-chunk via atomicMin on uint bits (values clamped >= 0,
// so uint ordering == float ordering).
__global__ __launch_bounds__(TPB)
void chamfer_partial_min(const float* __restrict__ pred,
                         const float* __restrict__ tgt,
                         unsigned int* __restrict__ mins /* [2][BATCH*NPTS] */)
{
    int bid = blockIdx.x;
    const int per_dir = BATCH * NQT * NCH;
    int dir = bid / per_dir;
    int r   = bid - dir * per_dir;
    int b   = r / (NQT * NCH);
    r      -= b * (NQT * NCH);
    int qt  = r / NCH;
    int ch  = r - qt * NCH;

    const float* qsrc = dir ? tgt  : pred;
    const float* csrc = dir ? pred : tgt;
    unsigned int* mout = mins + (size_t)dir * (BATCH * NPTS) + (size_t)b * NPTS;

    __shared__ float4 sc[CHUNK];
    {
        const float* cbase = csrc + (size_t)(b * NPTS + ch * CHUNK) * 3;
        for (int p = threadIdx.x; p < CHUNK; p += TPB) {
            float x = cbase[3 * p + 0];
            float y = cbase[3 * p + 1];
            float z = cbase[3 * p + 2];
            sc[p] = make_float4(x, y, z, x * x + y * y + z * z);
        }
    }
    __syncthreads();

    float ax[Q], ay[Q], az[Q], w[Q], mn[Q];
    const int q0 = qt * QTILE + threadIdx.x;
#pragma unroll
    for (int i = 0; i < Q; ++i) {
        int q = q0 + i * TPB;
        const float* qp = qsrc + (size_t)(b * NPTS + q) * 3;
        float x = qp[0], y = qp[1], z = qp[2];
        ax[i] = -2.0f * x;
        ay[i] = -2.0f * y;
        az[i] = -2.0f * z;
        w[i]  = x * x + y * y + z * z;
        mn[i] = 3.0e38f;
    }

#pragma unroll 4
    for (int j = 0; j < CHUNK; ++j) {
        float4 t = sc[j];   // uniform address -> ds_read_b128 broadcast
#pragma unroll
        for (int i = 0; i < Q; ++i) {
            float d = w[i] + t.w;
            d = fmaf(ax[i], t.x, d);
            d = fmaf(ay[i], t.y, d);
            d = fmaf(az[i], t.z, d);
            mn[i] = fminf(mn[i], d);
        }
    }

#pragma unroll
    for (int i = 0; i < Q; ++i) {
        int q = q0 + i * TPB;
        atomicMin(&mout[q], __float_as_uint(fmaxf(mn[i], 0.0f)));
    }
}

// Final reduce: two means over BATCH*NPTS mins each, write scalar.
__global__ __launch_bounds__(1024)
void chamfer_reduce(const unsigned int* __restrict__ mins,
                    float* __restrict__ out)
{
    float s0 = 0.0f, s1 = 0.0f;
    for (int i = threadIdx.x; i < BATCH * NPTS; i += 1024) {
        s0 += __uint_as_float(mins[i]);
        s1 += __uint_as_float(mins[BATCH * NPTS + i]);
    }
#pragma unroll
    for (int o = 32; o; o >>= 1) {
        s0 += __shfl_down(s0, o);
        s1 += __shfl_down(s1, o);
    }
    __shared__ float a0[16], a1[16];
    int lane = threadIdx.x & 63, wid = threadIdx.x >> 6;
    if (lane == 0) { a0[wid] = s0; a1[wid] = s1; }
    __syncthreads();
    if (threadIdx.x == 0) {
        float t0 = 0.0f, t1 = 0.0f;
#pragma unroll
        for (int i = 0; i < 16; ++i) { t0 += a0[i]; t1 += a1[i]; }
        out[0] = t0 * (1.0f / (BATCH * NPTS)) + t1 * (1.0f / (BATCH * NPTS));
    }
}

// Fallback (no workspace): each block owns TPB queries over full M, loops
// target chunks in LDS, block-reduces the sum of mins, atomicAdd into out.
__global__ __launch_bounds__(TPB)
void chamfer_fallback(const float* __restrict__ pred,
                      const float* __restrict__ tgt,
                      float* __restrict__ out)
{
    int bid = blockIdx.x;
    const int per_dir = BATCH * (NPTS / TPB);
    int dir = bid / per_dir;
    int r   = bid - dir * per_dir;
    int b   = r / (NPTS / TPB);
    int qt  = r % (NPTS / TPB);

    const float* qsrc = dir ? tgt  : pred;
    const float* csrc = dir ? pred : tgt;

    __shared__ float4 sc[CHUNK];

    int q = qt * TPB + threadIdx.x;
    const float* qp = qsrc + (size_t)(b * NPTS + q) * 3;
    float x = qp[0], y = qp[1], z = qp[2];
    float ax = -2.0f * x, ay = -2.0f * y, az = -2.0f * z;
    float w = x * x + y * y + z * z;
    float mn = 3.0e38f;

    for (int ch = 0; ch < NCH; ++ch) {
        __syncthreads();
        const float* cbase = csrc + (size_t)(b * NPTS + ch * CHUNK) * 3;
        for (int p = threadIdx.x; p < CHUNK; p += TPB) {
            float tx = cbase[3 * p + 0];
            float ty = cbase[3 * p + 1];
            float tz = cbase[3 * p + 2];
            sc[p] = make_float4(tx, ty, tz, tx * tx + ty * ty + tz * tz);
        }
        __syncthreads();
#pragma unroll 4
        for (int j = 0; j < CHUNK; ++j) {
            float4 t = sc[j];
            float d = w + t.w;
            d = fmaf(ax, t.x, d);
            d = fmaf(ay, t.y, d);
            d = fmaf(az, t.z, d);
            mn = fminf(mn, d);
        }
    }
    mn = fmaxf(mn, 0.0f);

#pragma unroll
    for (int o = 32; o; o >>= 1) mn += __shfl_down(mn, o);
    __shared__ float acc[TPB / 64];
    int lane = threadIdx.x & 63, wid = threadIdx.x >> 6;
    if (lane == 0) acc[wid] = mn;
    __syncthreads();
    if (threadIdx.x == 0) {
        float s = 0.0f;
#pragma unroll
        for (int i = 0; i < TPB / 64; ++i) s += acc[i];
        atomicAdd(out, s * (1.0f / (BATCH * NPTS)));
    }
}

extern "C" void kernel_launch(void* const* d_in, const int* in_sizes, int n_in,
                              void* d_out, int out_size, void* d_ws, size_t ws_size,
                              hipStream_t stream)
{
    const float* pred = (const float*)d_in[0];
    const float* tgt  = (const float*)d_in[1];
    float* out = (float*)d_out;

    const size_t need = (size_t)2 * BATCH * NPTS * sizeof(unsigned int); // 256 KB
    if (ws_size >= need) {
        unsigned int* mins = (unsigned int*)d_ws;
        // 0x7F7F7F7F == 3.39e38f: valid huge float, uint-order consistent.
        hipMemsetAsync(d_ws, 0x7F, need, stream);
        chamfer_partial_min<<<2 * BATCH * NQT * NCH, TPB, 0, stream>>>(pred, tgt, mins);
        chamfer_reduce<<<1, 1024, 0, stream>>>(mins, out);
    } else {
        hipMemsetAsync(d_out, 0, sizeof(float), stream);
        chamfer_fallback<<<2 * BATCH * (NPTS / TPB), TPB, 0, stream>>>(pred, tgt, out);
    }
}

// Round 2
// 37.931 us; speedup vs baseline: 1.6466x; 1.6466x over previous
//
#include <hip/hip_runtime.h>

// Chamfer loss: pred (8,4096,3) f32, target (8,4096,3) f32 -> scalar f32.
// Per pair: dist = q^2 + (t^2 - 2 q.t). The loop computes m = min_t (t^2 - 2q.t)
// as a pure FMA chain seeded from t.w; q^2 added once after the loop.

#define BATCH 8
#define NPTS  4096
#define TPB   256
#define Q     8                    // queries per thread
#define QTILE (TPB * Q)            // 2048 queries per block
#define NQT   (NPTS / QTILE)       // 2
#define NQ_TOTAL (2 * BATCH * NPTS) // 65536 query slots (both directions)

// ---- primary path: dense per-chunk slots, no atomics in the hot kernel ----
#define NCH2   32
#define CHUNK2 (NPTS / NCH2)       // 128 targets staged per block

__global__ __launch_bounds__(TPB, 4)
void chamfer_min_slots(const float* __restrict__ pred,
                       const float* __restrict__ tgt,
                       float* __restrict__ part /* [NCH2][NQ_TOTAL] */)
{
    int bid = blockIdx.x;
    const int per_dir = BATCH * NQT * NCH2;       // 512
    int dir = bid / per_dir;
    int r   = bid - dir * per_dir;
    int b   = r / (NQT * NCH2);
    r      -= b * (NQT * NCH2);
    int qt  = r / NCH2;
    int ch  = r - qt * NCH2;

    const float* qsrc = dir ? tgt  : pred;
    const float* csrc = dir ? pred : tgt;

    __shared__ float4 sc[CHUNK2];
    {
        const float* cbase = csrc + (size_t)(b * NPTS + ch * CHUNK2) * 3;
        for (int p = threadIdx.x; p < CHUNK2; p += TPB) {
            float x = cbase[3 * p + 0];
            float y = cbase[3 * p + 1];
            float z = cbase[3 * p + 2];
            sc[p] = make_float4(x, y, z, x * x + y * y + z * z);
        }
    }
    __syncthreads();

    float ax[Q], ay[Q], az[Q], w[Q], mn[Q];
    const int q0 = qt * QTILE + threadIdx.x;
#pragma unroll
    for (int i = 0; i < Q; ++i) {
        int q = q0 + i * TPB;
        const float* qp = qsrc + (size_t)(b * NPTS + q) * 3;
        float x = qp[0], y = qp[1], z = qp[2];
        ax[i] = -2.0f * x;
        ay[i] = -2.0f * y;
        az[i] = -2.0f * z;
        w[i]  = x * x + y * y + z * z;
        mn[i] = 3.0e38f;
    }

    // 2 targets per iteration -> v_min3_f32; 3 FMA + ~0.5 min per pair.
#pragma unroll 4
    for (int j = 0; j < CHUNK2; j += 2) {
        float4 t0 = sc[j];       // uniform addr -> ds_read_b128 broadcast
        float4 t1 = sc[j + 1];
#pragma unroll
        for (int i = 0; i < Q; ++i) {
            float d0 = fmaf(az[i], t0.z, fmaf(ay[i], t0.y, fmaf(ax[i], t0.x, t0.w)));
            float d1 = fmaf(az[i], t1.z, fmaf(ay[i], t1.y, fmaf(ax[i], t1.x, t1.w)));
            mn[i] = fminf(fminf(d0, d1), mn[i]);   // fuses to v_min3_f32
        }
    }

    float* pslot = part + (size_t)ch * NQ_TOTAL
                 + (size_t)dir * (BATCH * NPTS) + (size_t)b * NPTS;
#pragma unroll
    for (int i = 0; i < Q; ++i)
        pslot[q0 + i * TPB] = w[i] + mn[i];        // coalesced, no atomics
}

// min across NCH2 chunks, then mean. mean0+mean1 == sum(all)/32768.
__global__ __launch_bounds__(TPB)
void chamfer_reduce_slots(const float* __restrict__ part,
                          float* __restrict__ out)
{
    const int nthreads = gridDim.x * TPB;         // 16384
    int idx = blockIdx.x * TPB + threadIdx.x;
    float s = 0.0f;
    for (int q = idx; q < NQ_TOTAL; q += nthreads) {
        float m = part[q];
#pragma unroll
        for (int c = 1; c < NCH2; ++c)
            m = fminf(m, part[(size_t)c * NQ_TOTAL + q]);
        s += m;
    }
#pragma unroll
    for (int o = 32; o; o >>= 1) s += __shfl_down(s, o);
    __shared__ float acc[TPB / 64];
    int lane = threadIdx.x & 63, wid = threadIdx.x >> 6;
    if (lane == 0) acc[wid] = s;
    __syncthreads();
    if (threadIdx.x == 0) {
        float t = 0.0f;
#pragma unroll
        for (int i = 0; i < TPB / 64; ++i) t += acc[i];
        atomicAdd(out, t * (1.0f / (BATCH * NPTS)));
    }
}

// ---- secondary path (256 KB ws): atomicMin on uint-encoded nonneg floats ----
#define CHUNK 512
#define NCH   (NPTS / CHUNK)

__global__ __launch_bounds__(TPB)
void chamfer_partial_min(const float* __restrict__ pred,
                         const float* __restrict__ tgt,
                         unsigned int* __restrict__ mins)
{
    int bid = blockIdx.x;
    const int per_dir = BATCH * NQT * NCH;
    int dir = bid / per_dir;
    int r   = bid - dir * per_dir;
    int b   = r / (NQT * NCH);
    r      -= b * (NQT * NCH);
    int qt  = r / NCH;
    int ch  = r - qt * NCH;

    const float* qsrc = dir ? tgt  : pred;
    const float* csrc = dir ? pred : tgt;
    unsigned int* mout = mins + (size_t)dir * (BATCH * NPTS) + (size_t)b * NPTS;

    __shared__ float4 sc[CHUNK];
    {
        const float* cbase = csrc + (size_t)(b * NPTS + ch * CHUNK) * 3;
        for (int p = threadIdx.x; p < CHUNK; p += TPB) {
            float x = cbase[3 * p + 0];
            float y = cbase[3 * p + 1];
            float z = cbase[3 * p + 2];
            sc[p] = make_float4(x, y, z, x * x + y * y + z * z);
        }
    }
    __syncthreads();

    float ax[Q], ay[Q], az[Q], w[Q], mn[Q];
    const int q0 = qt * QTILE + threadIdx.x;
#pragma unroll
    for (int i = 0; i < Q; ++i) {
        int q = q0 + i * TPB;
        const float* qp = qsrc + (size_t)(b * NPTS + q) * 3;
        float x = qp[0], y = qp[1], z = qp[2];
        ax[i] = -2.0f * x; ay[i] = -2.0f * y; az[i] = -2.0f * z;
        w[i]  = x * x + y * y + z * z;
        mn[i] = 3.0e38f;
    }
#pragma unroll 4
    for (int j = 0; j < CHUNK; j += 2) {
        float4 t0 = sc[j], t1 = sc[j + 1];
#pragma unroll
        for (int i = 0; i < Q; ++i) {
            float d0 = fmaf(az[i], t0.z, fmaf(ay[i], t0.y, fmaf(ax[i], t0.x, t0.w)));
            float d1 = fmaf(az[i], t1.z, fmaf(ay[i], t1.y, fmaf(ax[i], t1.x, t1.w)));
            mn[i] = fminf(fminf(d0, d1), mn[i]);
        }
    }
#pragma unroll
    for (int i = 0; i < Q; ++i)
        atomicMin(&mout[q0 + i * TPB], __float_as_uint(fmaxf(w[i] + mn[i], 0.0f)));
}

__global__ __launch_bounds__(1024)
void chamfer_reduce(const unsigned int* __restrict__ mins,
                    float* __restrict__ out)
{
    float s0 = 0.0f, s1 = 0.0f;
    for (int i = threadIdx.x; i < BATCH * NPTS; i += 1024) {
        s0 += __uint_as_float(mins[i]);
        s1 += __uint_as_float(mins[BATCH * NPTS + i]);
    }
#pragma unroll
    for (int o = 32; o; o >>= 1) { s0 += __shfl_down(s0, o); s1 += __shfl_down(s1, o); }
    __shared__ float a0[16], a1[16];
    int lane = threadIdx.x & 63, wid = threadIdx.x >> 6;
    if (lane == 0) { a0[wid] = s0; a1[wid] = s1; }
    __syncthreads();
    if (threadIdx.x == 0) {
        float t0 = 0.0f, t1 = 0.0f;
#pragma unroll
        for (int i = 0; i < 16; ++i) { t0 += a0[i]; t1 += a1[i]; }
        out[0] = (t0 + t1) * (1.0f / (BATCH * NPTS));
    }
}

// ---- tertiary path (no usable ws) ----
__global__ __launch_bounds__(TPB)
void chamfer_fallback(const float* __restrict__ pred,
                      const float* __restrict__ tgt,
                      float* __restrict__ out)
{
    int bid = blockIdx.x;
    const int per_dir = BATCH * (NPTS / TPB);
    int dir = bid / per_dir;
    int r   = bid - dir * per_dir;
    int b   = r / (NPTS / TPB);
    int qt  = r % (NPTS / TPB);

    const float* qsrc = dir ? tgt  : pred;
    const float* csrc = dir ? pred : tgt;

    __shared__ float4 sc[CHUNK];
    int q = qt * TPB + threadIdx.x;
    const float* qp = qsrc + (size_t)(b * NPTS + q) * 3;
    float x = qp[0], y = qp[1], z = qp[2];
    float ax = -2.0f * x, ay = -2.0f * y, az = -2.0f * z;
    float w = x * x + y * y + z * z;
    float mn = 3.0e38f;

    for (int ch = 0; ch < NCH; ++ch) {
        __syncthreads();
        const float* cbase = csrc + (size_t)(b * NPTS + ch * CHUNK) * 3;
        for (int p = threadIdx.x; p < CHUNK; p += TPB) {
            float tx = cbase[3 * p + 0];
            float ty = cbase[3 * p + 1];
            float tz = cbase[3 * p + 2];
            sc[p] = make_float4(tx, ty, tz, tx * tx + ty * ty + tz * tz);
        }
        __syncthreads();
#pragma unroll 4
        for (int j = 0; j < CHUNK; ++j) {
            float4 t = sc[j];
            float d = fmaf(az, t.z, fmaf(ay, t.y, fmaf(ax, t.x, t.w)));
            mn = fminf(mn, d);
        }
    }
    mn += w;
#pragma unroll
    for (int o = 32; o; o >>= 1) mn += __shfl_down(mn, o);
    __shared__ float acc[TPB / 64];
    int lane = threadIdx.x & 63, wid = threadIdx.x >> 6;
    if (lane == 0) acc[wid] = mn;
    __syncthreads();
    if (threadIdx.x == 0) {
        float s = 0.0f;
#pragma unroll
        for (int i = 0; i < TPB / 64; ++i) s += acc[i];
        atomicAdd(out, s * (1.0f / (BATCH * NPTS)));
    }
}

extern "C" void kernel_launch(void* const* d_in, const int* in_sizes, int n_in,
                              void* d_out, int out_size, void* d_ws, size_t ws_size,
                              hipStream_t stream)
{
    const float* pred = (const float*)d_in[0];
    const float* tgt  = (const float*)d_in[1];
    float* out = (float*)d_out;

    const size_t need_slots = (size_t)NCH2 * NQ_TOTAL * sizeof(float);   // 8 MB
    const size_t need_amin  = (size_t)NQ_TOTAL * sizeof(unsigned int);   // 256 KB

    if (ws_size >= need_slots) {
        float* part = (float*)d_ws;
        hipMemsetAsync(d_out, 0, sizeof(float), stream);
        chamfer_min_slots<<<2 * BATCH * NQT * NCH2, TPB, 0, stream>>>(pred, tgt, part);
        chamfer_reduce_slots<<<64, TPB, 0, stream>>>(part, out);
    } else if (ws_size >= need_amin) {
        unsigned int* mins = (unsigned int*)d_ws;
        hipMemsetAsync(d_ws, 0x7F, need_amin, stream);
        chamfer_partial_min<<<2 * BATCH * NQT * NCH, TPB, 0, stream>>>(pred, tgt, mins);
        chamfer_reduce<<<1, 1024, 0, stream>>>(mins, out);
    } else {
        hipMemsetAsync(d_out, 0, sizeof(float), stream);
        chamfer_fallback<<<2 * BATCH * (NPTS / TPB), TPB, 0, stream>>>(pred, tgt, out);
    }
}